// Round 9
// baseline (1816.189 us; speedup 1.0000x reference)
//
#include <hip/hip_runtime.h>

#define NB 8
#define CH 8
#define N1S 255
#define CROP 257
#define NOUT 255
#define CC (CROP * CROP)   // 66049

static constexpr float PI2 = 6.28318530717958647692f;

__device__ inline unsigned short f2bf(float f) {
  unsigned int u = __float_as_uint(f);
  unsigned int lsb = (u >> 16) & 1u;
  u += 0x7fffu + lsb;
  return (unsigned short)(u >> 16);
}

__global__ void k_fill(unsigned short* __restrict__ out, int n, float v) {
  int i = blockIdx.x * 256 + threadIdx.x;
  if (i < n) out[i] = f2bf(v);
}

// ---------------- trig tables ----------------
__global__ void k_tables(float* __restrict__ T, float* __restrict__ Tt,
                         float2* __restrict__ D, float2* __restrict__ Dt) {
  int idx = blockIdx.x * blockDim.x + threadIdx.x;
  if (idx < CROP * N1S) {
    int a = idx / N1S, p = idx % N1S;
    int v = (p + 1) * (a - 128);
    int t = v % 512; if (t < 0) t += 512; if (t >= 256) t -= 512;
    float s = sinf((float)t * (PI2 / 512.0f));
    T[a * N1S + p] = s;
    Tt[p * CROP + a] = s;
  }
  if (idx < NOUT * CROP) {
    int k = idx / CROP, j = idx % CROP;
    int v = k * (j - 127);
    int t = v % 513; if (t < 0) t += 513; if (t > 256) t -= 513;
    float ang = (float)t * (PI2 / 513.0f);
    float2 d = make_float2(cosf(ang), -sinf(ang));
    D[k * CROP + j] = d;
    Dt[j * NOUT + k] = d;
  }
}

// ---------------- DST front transform (validated == literal ifft path) ----------------
__global__ __launch_bounds__(256) void k_dst1(const float* __restrict__ r,
                                              const float* __restrict__ T,
                                              float* __restrict__ tmp) {
  int n = blockIdx.x * 64 + threadIdx.x;
  int a = blockIdx.y * 4 + threadIdx.y;
  int b = blockIdx.z;
  if (n >= N1S || a >= CROP) return;
  const float* rb = r + b * N1S * N1S;
  const float* Ta = T + a * N1S;
  float acc = 0.f;
  #pragma unroll 5
  for (int m = 0; m < N1S; ++m)
    acc = fmaf(Ta[m], rb[m * N1S + n], acc);
  tmp[(b * CROP + a) * N1S + n] = acc;
}

__global__ __launch_bounds__(256) void k_dst2(const float* __restrict__ tmp,
                                              const float* __restrict__ Tt,
                                              float2* __restrict__ z0) {
  int a2 = blockIdx.x * 64 + threadIdx.x;
  int a1 = blockIdx.y * 4 + threadIdx.y;
  int b = blockIdx.z;
  if (a2 >= CROP || a1 >= CROP) return;
  const float* tb = tmp + (b * CROP + a1) * N1S;
  float acc = 0.f;
  #pragma unroll 5
  for (int n = 0; n < N1S; ++n)
    acc = fmaf(tb[n], Tt[n * CROP + a2], acc);
  z0[(b * CROP + a1) * CROP + a2] = make_float2(acc * (-1.0f / 65536.0f), 0.f);
}

// ---------------- literal per-sample conv (validated vs tiled) ----------------
template<int CIN, int COUT, bool TRANS>
__global__ void k_conv_dumb(const float2* __restrict__ in,
                            const float* __restrict__ wre,
                            const float* __restrict__ wim,
                            float2* __restrict__ out, int b) {
  int idx = blockIdx.x * 256 + threadIdx.x;
  if (idx >= COUT * CC) return;
  int o = idx / CC, rem = idx % CC;
  int y = rem / CROP, x = rem % CROP;
  float ar = 0.f, ai = 0.f;
  for (int c = 0; c < CIN; ++c)
    for (int di = 0; di < 3; ++di)
      for (int dj = 0; dj < 3; ++dj) {
        int yy = y + di - 1, xx = x + dj - 1;
        if (yy < 0 || yy >= CROP || xx < 0 || xx >= CROP) continue;
        float2 v = in[(c * CROP + yy) * CROP + xx];
        int widx;
        if (TRANS) widx = (((b * CIN + c) * COUT + o) * 3 + dj) * 3 + di;
        else       widx = (((b * COUT + o) * CIN + c) * 3 + di) * 3 + dj;
        float wr = wre[widx];
        float wi = TRANS ? -wim[widx] : wim[widx];
        ar += wr * v.x - wi * v.y;
        ai += wr * v.y + wi * v.x;
      }
  out[idx] = make_float2(ar, ai);
}

__global__ void k_theta(const float2* __restrict__ u, const float* __restrict__ tre,
                        const float* __restrict__ tim, float2* __restrict__ v, int n) {
  int idx = blockIdx.x * 256 + threadIdx.x;
  if (idx >= n) return;
  float2 a = u[idx];
  float br = tre[idx], bi = tim[idx];
  v[idx] = make_float2(a.x * br - a.y * bi, a.x * bi + a.y * br);
}

// ---------------- back transform (validated == literal path) ----------------
__global__ __launch_bounds__(256) void k_f1(const float2* __restrict__ z,
                                            const float2* __restrict__ D,
                                            float2* __restrict__ t) {
  int j2 = blockIdx.x * 64 + threadIdx.x;
  int k  = blockIdx.y * 4 + threadIdx.y;
  int b  = blockIdx.z;
  if (j2 >= CROP || k >= NOUT) return;
  const float2* zb = z + (size_t)b * CC;
  const float2* Dk = D + k * CROP;
  float tr = 0.f, ti = 0.f;
  #pragma unroll 4
  for (int j1 = 0; j1 < CROP; ++j1) {
    float2 d = Dk[j1];
    float2 zv = zb[j1 * CROP + j2];
    tr = fmaf(d.x, zv.x, tr); tr = fmaf(-d.y, zv.y, tr);
    ti = fmaf(d.x, zv.y, ti); ti = fmaf(d.y, zv.x, ti);
  }
  t[((size_t)b * NOUT + k) * CROP + j2] = make_float2(tr, ti);
}

// PAIR-SWAP test: write (im, re) per element, interleaved
__global__ __launch_bounds__(256) void k_f2(const float2* __restrict__ t,
                                            const float2* __restrict__ Dt,
                                            ushort2* __restrict__ out) {
  int k2 = blockIdx.x * 64 + threadIdx.x;
  int k1 = blockIdx.y * 4 + threadIdx.y;
  int b  = blockIdx.z;
  if (k2 >= NOUT || k1 >= NOUT) return;
  const float2* tb = t + ((size_t)b * NOUT + k1) * CROP;
  float er = 0.f, ei = 0.f;
  #pragma unroll 4
  for (int j2 = 0; j2 < CROP; ++j2) {
    float2 tv = tb[j2];
    float2 d = Dt[j2 * NOUT + k2];
    er = fmaf(tv.x, d.x, er); er = fmaf(-tv.y, d.y, er);
    ei = fmaf(tv.x, d.y, ei); ei = fmaf(tv.y, d.x, ei);
  }
  out[((size_t)b * NOUT + k1) * NOUT + k2] = make_ushort2(f2bf(ei), f2bf(er));
}

extern "C" void kernel_launch(void* const* d_in, const int* in_sizes, int n_in,
                              void* d_out, int out_size, void* d_ws, size_t ws_size,
                              hipStream_t stream) {
  (void)ws_size;
  static const int EXP[9] = {520200, 576, 576, 4608, 4608, 4608, 4608, 4227136, 4227136};
  int bad = -1;
  if (n_in != 9) bad = 90;
  else for (int i = 0; i < 9; ++i) if (in_sizes[i] != EXP[i]) { bad = i; break; }
  if (bad >= 0) {
    float v = (bad == 90) ? 99.0f : (100.0f + (float)bad);
    k_fill<<<(out_size + 255) / 256, 256, 0, stream>>>((unsigned short*)d_out, out_size, v);
    return;
  }

  const float* r    = (const float*)d_in[0];
  const float* w1re = (const float*)d_in[1];
  const float* w1im = (const float*)d_in[2];
  const float* w2re = (const float*)d_in[3];
  const float* w2im = (const float*)d_in[4];
  const float* w3re = (const float*)d_in[5];
  const float* w3im = (const float*)d_in[6];
  const float* thre = (const float*)d_in[7];
  const float* thim = (const float*)d_in[8];

  float* ws = (float*)d_ws;
  size_t off = 0;
  auto alloc = [&](size_t n) { float* p = ws + off; off += (n + 63) & ~(size_t)63; return p; };
  float*  T    = alloc((size_t)CROP * N1S);
  float*  Tt   = alloc((size_t)N1S * CROP);
  float2* D    = (float2*)alloc((size_t)NOUT * CROP * 2);
  float2* Dt   = (float2*)alloc((size_t)CROP * NOUT * 2);
  float*  tmpA = alloc((size_t)NB * CROP * N1S);
  float2* z0   = (float2*)alloc((size_t)NB * CC * 2);
  float2* tmpF = (float2*)alloc((size_t)NB * NOUT * CROP * 2);
  float2* A2   = (float2*)alloc((size_t)CH * CC * 2);
  float2* B2   = (float2*)alloc((size_t)CH * CC * 2);

  k_tables<<<dim3((CROP * N1S + 255) / 256), dim3(256), 0, stream>>>(T, Tt, D, Dt);
  k_dst1<<<dim3(4, 65, NB), dim3(64, 4), 0, stream>>>(r, T, tmpA);
  k_dst2<<<dim3(5, 65, NB), dim3(64, 4), 0, stream>>>(tmpA, Tt, z0);

  const int nth = CH * CC;
  const int g8 = (CH * CC + 255) / 256, g1 = (CC + 255) / 256;
  for (int b = 0; b < NB; ++b) {
    float2* zb = z0 + (size_t)b * CC;
    k_conv_dumb<1, 8, false><<<g8, 256, 0, stream>>>(zb, w1re, w1im, A2, b);
    k_conv_dumb<8, 8, false><<<g8, 256, 0, stream>>>(A2, w2re, w2im, B2, b);
    k_conv_dumb<8, 8, false><<<g8, 256, 0, stream>>>(B2, w3re, w3im, A2, b);
    k_theta<<<(nth + 255) / 256, 256, 0, stream>>>(A2, thre + (size_t)b * nth, thim + (size_t)b * nth, B2, nth);
    k_conv_dumb<8, 8, true><<<g8, 256, 0, stream>>>(B2, w3re, w3im, A2, b);
    k_conv_dumb<8, 8, true><<<g8, 256, 0, stream>>>(A2, w2re, w2im, B2, b);
    k_conv_dumb<8, 1, true><<<g1, 256, 0, stream>>>(B2, w1re, w1im, zb, b);
  }

  k_f1<<<dim3(5, 64, NB), dim3(64, 4), 0, stream>>>(z0, D, tmpF);
  k_f2<<<dim3(4, 64, NB), dim3(64, 4), 0, stream>>>(tmpF, Dt, (ushort2*)d_out);
}

// Round 10
// 495.048 us; speedup vs baseline: 3.6687x; 3.6687x over previous
//
#include <hip/hip_runtime.h>

#define NB 8
#define CH 8
#define N1S 255
#define CROP 257
#define NOUT 255
#define CC (CROP * CROP)   // 66049

static constexpr float PI2 = 6.28318530717958647692f;

__device__ inline unsigned short f2bf(float f) {
  unsigned int u = __float_as_uint(f);
  unsigned int lsb = (u >> 16) & 1u;
  u += 0x7fffu + lsb;
  return (unsigned short)(u >> 16);
}

__global__ void k_fill(unsigned short* __restrict__ out, int n, float v) {
  int i = blockIdx.x * 256 + threadIdx.x;
  if (i < n) out[i] = f2bf(v);
}

// ---------------- trig tables ----------------
__global__ void k_tables(float* __restrict__ T, float* __restrict__ Tt,
                         float2* __restrict__ D, float2* __restrict__ Dt) {
  int idx = blockIdx.x * blockDim.x + threadIdx.x;
  if (idx < CROP * N1S) {
    int a = idx / N1S, p = idx % N1S;
    int v = (p + 1) * (a - 128);
    int t = v % 512; if (t < 0) t += 512; if (t >= 256) t -= 512;
    float s = sinf((float)t * (PI2 / 512.0f));
    T[a * N1S + p] = s;
    Tt[p * CROP + a] = s;
  }
  if (idx < NOUT * CROP) {
    int k = idx / CROP, j = idx % CROP;
    int v = k * (j - 127);
    int t = v % 513; if (t < 0) t += 513; if (t > 256) t -= 513;
    float ang = (float)t * (PI2 / 513.0f);
    float2 d = make_float2(cosf(ang), -sinf(ang));
    D[k * CROP + j] = d;
    Dt[j * NOUT + k] = d;
  }
}

// ---------------- DST front transform: 4 outputs/thread ----------------
// tmp[b,a,n] = sum_m T[a,m] * r[b,m,n]
__global__ __launch_bounds__(256) void k_dst1(const float* __restrict__ r,
                                              const float* __restrict__ T,
                                              float* __restrict__ tmp) {
  int n  = blockIdx.x * 64 + threadIdx.x;
  int a0 = blockIdx.y * 16 + threadIdx.y * 4;
  int b  = blockIdx.z;
  if (n >= N1S) return;
  int ac[4];
  #pragma unroll
  for (int q = 0; q < 4; ++q) ac[q] = (a0 + q < CROP) ? (a0 + q) : (CROP - 1);
  const float* rb = r + (size_t)b * N1S * N1S;
  float acc[4] = {0.f, 0.f, 0.f, 0.f};
  for (int m = 0; m < N1S; ++m) {
    float x = rb[m * N1S + n];
    #pragma unroll
    for (int q = 0; q < 4; ++q)
      acc[q] = fmaf(T[ac[q] * N1S + m], x, acc[q]);
  }
  #pragma unroll
  for (int q = 0; q < 4; ++q)
    if (a0 + q < CROP) tmp[((size_t)b * CROP + a0 + q) * N1S + n] = acc[q];
}

// z0[b,a1,a2] = -(4/512^2) sum_n tmp[b,a1,n] * Tt[n,a2]
__global__ __launch_bounds__(256) void k_dst2(const float* __restrict__ tmp,
                                              const float* __restrict__ Tt,
                                              float2* __restrict__ z0) {
  int a2  = blockIdx.x * 64 + threadIdx.x;
  int a10 = blockIdx.y * 16 + threadIdx.y * 4;
  int b   = blockIdx.z;
  if (a2 >= CROP) return;
  int ac[4];
  #pragma unroll
  for (int q = 0; q < 4; ++q) ac[q] = (a10 + q < CROP) ? (a10 + q) : (CROP - 1);
  const float* tb = tmp + (size_t)b * CROP * N1S;
  float acc[4] = {0.f, 0.f, 0.f, 0.f};
  for (int n = 0; n < N1S; ++n) {
    float tv = Tt[n * CROP + a2];
    #pragma unroll
    for (int q = 0; q < 4; ++q)
      acc[q] = fmaf(tb[ac[q] * N1S + n], tv, acc[q]);
  }
  #pragma unroll
  for (int q = 0; q < 4; ++q)
    if (a10 + q < CROP)
      z0[((size_t)b * CROP + a10 + q) * CROP + a2] = make_float2(acc[q] * (-1.0f / 65536.0f), 0.f);
}

// ---------------- batched tiled complex 3x3 conv (validated) ----------------
template<int CIN, int COUT, bool TRANS>
__global__ __launch_bounds__(256) void k_conv(const float2* __restrict__ in,
                                              const float* __restrict__ wre,
                                              const float* __restrict__ wim,
                                              float2* __restrict__ out) {
  __shared__ float2 tile[CIN][18][18];
  __shared__ float2 wsh[COUT * CIN * 9];
  const int b = blockIdx.z;
  const int tx = threadIdx.x, ty = threadIdx.y;
  const int tid = ty * 16 + tx;
  const int ox0 = blockIdx.x * 16, oy0 = blockIdx.y * 16;

  for (int idx = tid; idx < COUT * CIN * 9; idx += 256) {
    int o = idx / (CIN * 9);
    int rem = idx % (CIN * 9);
    int c = rem / 9, tap = rem % 9;
    int di = tap / 3, dj = tap % 3;
    int widx; float sgn;
    if (TRANS) { widx = (((b * CIN + c) * COUT + o) * 3 + dj) * 3 + di; sgn = -1.f; }
    else       { widx = (((b * COUT + o) * CIN + c) * 3 + di) * 3 + dj; sgn = 1.f; }
    wsh[idx] = make_float2(wre[widx], sgn * wim[widx]);
  }
  const float2* inb = in + (size_t)b * CIN * CC;
  for (int c = 0; c < CIN; ++c) {
    for (int idx = tid; idx < 18 * 18; idx += 256) {
      int iy = idx / 18, ix = idx % 18;
      int gy = oy0 + iy - 1, gx = ox0 + ix - 1;
      float2 v = make_float2(0.f, 0.f);
      if (gy >= 0 && gy < CROP && gx >= 0 && gx < CROP)
        v = inb[(c * CROP + gy) * CROP + gx];
      tile[c][iy][ix] = v;
    }
  }
  __syncthreads();
  const int ox = ox0 + tx, oy = oy0 + ty;
  if (ox >= CROP || oy >= CROP) return;
  float accr[COUT], acci[COUT];
  #pragma unroll
  for (int o = 0; o < COUT; ++o) { accr[o] = 0.f; acci[o] = 0.f; }
  for (int c = 0; c < CIN; ++c) {
    float xr[9], xi[9];
    #pragma unroll
    for (int t9 = 0; t9 < 9; ++t9) {
      float2 v = tile[c][ty + t9 / 3][tx + t9 % 3];
      xr[t9] = v.x; xi[t9] = v.y;
    }
    #pragma unroll
    for (int o = 0; o < COUT; ++o) {
      #pragma unroll
      for (int t9 = 0; t9 < 9; ++t9) {
        float2 w = wsh[(o * CIN + c) * 9 + t9];
        accr[o] = fmaf(w.x, xr[t9], accr[o]);
        accr[o] = fmaf(-w.y, xi[t9], accr[o]);
        acci[o] = fmaf(w.x, xi[t9], acci[o]);
        acci[o] = fmaf(w.y, xr[t9], acci[o]);
      }
    }
  }
  float2* outb = out + (size_t)b * COUT * CC;
  #pragma unroll
  for (int o = 0; o < COUT; ++o)
    outb[(o * CROP + oy) * CROP + ox] = make_float2(accr[o], acci[o]);
}

// ---------------- theta elementwise (batched) ----------------
__global__ void k_theta(const float2* __restrict__ u, const float* __restrict__ tre,
                        const float* __restrict__ tim, float2* __restrict__ v, int n) {
  int idx = blockIdx.x * 256 + threadIdx.x;
  if (idx >= n) return;
  float2 a = u[idx];
  float br = tre[idx], bi = tim[idx];
  v[idx] = make_float2(a.x * br - a.y * bi, a.x * bi + a.y * br);
}

// ---------------- back transform: 4 outputs/thread ----------------
// t[b,k,j2] = sum_j1 D[k,j1] * z[b,j1,j2]
__global__ __launch_bounds__(256) void k_f1(const float2* __restrict__ z,
                                            const float2* __restrict__ D,
                                            float2* __restrict__ t) {
  int j2 = blockIdx.x * 64 + threadIdx.x;
  int k0 = blockIdx.y * 16 + threadIdx.y * 4;
  int b  = blockIdx.z;
  if (j2 >= CROP) return;
  int kc[4];
  #pragma unroll
  for (int q = 0; q < 4; ++q) kc[q] = (k0 + q < NOUT) ? (k0 + q) : (NOUT - 1);
  const float2* zb = z + (size_t)b * CC;
  float tr[4] = {0.f,0.f,0.f,0.f}, ti[4] = {0.f,0.f,0.f,0.f};
  for (int j1 = 0; j1 < CROP; ++j1) {
    float2 zv = zb[j1 * CROP + j2];
    #pragma unroll
    for (int q = 0; q < 4; ++q) {
      float2 d = D[kc[q] * CROP + j1];
      tr[q] = fmaf(d.x, zv.x, tr[q]); tr[q] = fmaf(-d.y, zv.y, tr[q]);
      ti[q] = fmaf(d.x, zv.y, ti[q]); ti[q] = fmaf(d.y, zv.x, ti[q]);
    }
  }
  #pragma unroll
  for (int q = 0; q < 4; ++q)
    if (k0 + q < NOUT)
      t[((size_t)b * NOUT + k0 + q) * CROP + j2] = make_float2(tr[q], ti[q]);
}

// e[b,k1,k2] = sum_j2 t[b,k1,j2] * Dt[j2,k2];  output packed (IM, RE) per element
__global__ __launch_bounds__(256) void k_f2(const float2* __restrict__ t,
                                            const float2* __restrict__ Dt,
                                            ushort2* __restrict__ out) {
  int k2  = blockIdx.x * 64 + threadIdx.x;
  int k10 = blockIdx.y * 16 + threadIdx.y * 4;
  int b   = blockIdx.z;
  if (k2 >= NOUT) return;
  int kc[4];
  #pragma unroll
  for (int q = 0; q < 4; ++q) kc[q] = (k10 + q < NOUT) ? (k10 + q) : (NOUT - 1);
  const float2* tb = t + (size_t)b * NOUT * CROP;
  float er[4] = {0.f,0.f,0.f,0.f}, ei[4] = {0.f,0.f,0.f,0.f};
  for (int j2 = 0; j2 < CROP; ++j2) {
    float2 d = Dt[j2 * NOUT + k2];
    #pragma unroll
    for (int q = 0; q < 4; ++q) {
      float2 tv = tb[kc[q] * CROP + j2];
      er[q] = fmaf(tv.x, d.x, er[q]); er[q] = fmaf(-tv.y, d.y, er[q]);
      ei[q] = fmaf(tv.x, d.y, ei[q]); ei[q] = fmaf(tv.y, d.x, ei[q]);
    }
  }
  #pragma unroll
  for (int q = 0; q < 4; ++q)
    if (k10 + q < NOUT)
      out[((size_t)b * NOUT + k10 + q) * NOUT + k2] = make_ushort2(f2bf(ei[q]), f2bf(er[q]));
}

extern "C" void kernel_launch(void* const* d_in, const int* in_sizes, int n_in,
                              void* d_out, int out_size, void* d_ws, size_t ws_size,
                              hipStream_t stream) {
  (void)ws_size;
  static const int EXP[9] = {520200, 576, 576, 4608, 4608, 4608, 4608, 4227136, 4227136};
  int bad = -1;
  if (n_in != 9) bad = 90;
  else for (int i = 0; i < 9; ++i) if (in_sizes[i] != EXP[i]) { bad = i; break; }
  if (bad >= 0) {
    float v = (bad == 90) ? 99.0f : (100.0f + (float)bad);
    k_fill<<<(out_size + 255) / 256, 256, 0, stream>>>((unsigned short*)d_out, out_size, v);
    return;
  }

  const float* r    = (const float*)d_in[0];
  const float* w1re = (const float*)d_in[1];
  const float* w1im = (const float*)d_in[2];
  const float* w2re = (const float*)d_in[3];
  const float* w2im = (const float*)d_in[4];
  const float* w3re = (const float*)d_in[5];
  const float* w3im = (const float*)d_in[6];
  const float* thre = (const float*)d_in[7];
  const float* thim = (const float*)d_in[8];

  float* ws = (float*)d_ws;
  size_t off = 0;
  auto alloc = [&](size_t n) { float* p = ws + off; off += (n + 63) & ~(size_t)63; return p; };
  float*  T    = alloc((size_t)CROP * N1S);
  float*  Tt   = alloc((size_t)N1S * CROP);
  float2* D    = (float2*)alloc((size_t)NOUT * CROP * 2);
  float2* Dt   = (float2*)alloc((size_t)CROP * NOUT * 2);
  float*  tmpA = alloc((size_t)NB * CROP * N1S);
  float2* z0   = (float2*)alloc((size_t)NB * CC * 2);
  float2* tmpF = (float2*)alloc((size_t)NB * NOUT * CROP * 2);
  float2* A    = (float2*)alloc((size_t)NB * CH * CC * 2);   // 33.8 MB (plan validated r1≡r4≡r5)
  float2* Bb   = (float2*)alloc((size_t)NB * CH * CC * 2);   // 33.8 MB

  k_tables<<<dim3((CROP * N1S + 255) / 256), dim3(256), 0, stream>>>(T, Tt, D, Dt);
  k_dst1<<<dim3(4, 17, NB), dim3(64, 4), 0, stream>>>(r, T, tmpA);
  k_dst2<<<dim3(5, 17, NB), dim3(64, 4), 0, stream>>>(tmpA, Tt, z0);

  dim3 cgrid(17, 17, NB), cblk(16, 16);
  const int ne = NB * CH * CC;
  k_conv<1, 8, false><<<cgrid, cblk, 0, stream>>>(z0, w1re, w1im, A);
  k_conv<8, 8, false><<<cgrid, cblk, 0, stream>>>(A, w2re, w2im, Bb);
  k_conv<8, 8, false><<<cgrid, cblk, 0, stream>>>(Bb, w3re, w3im, A);
  k_theta<<<(ne + 255) / 256, 256, 0, stream>>>(A, thre, thim, Bb, ne);
  k_conv<8, 8, true><<<cgrid, cblk, 0, stream>>>(Bb, w3re, w3im, A);
  k_conv<8, 8, true><<<cgrid, cblk, 0, stream>>>(A, w2re, w2im, Bb);
  k_conv<8, 1, true><<<cgrid, cblk, 0, stream>>>(Bb, w1re, w1im, z0);

  k_f1<<<dim3(5, 16, NB), dim3(64, 4), 0, stream>>>(z0, D, tmpF);
  k_f2<<<dim3(4, 16, NB), dim3(64, 4), 0, stream>>>(tmpF, Dt, (ushort2*)d_out);
}